// Round 2
// baseline (424.995 us; speedup 1.0000x reference)
//
#include <hip/hip_runtime.h>
#include <hip/hip_bf16.h>
#include <math.h>

#define BN 32
#define L 128
#define D 128
#define TT 127
#define NH 8

__device__ __forceinline__ float fast_gelu(float x) {
    // tanh-form gelu: 0.5x(1+tanh(0.79788456(x+0.044715x^3)))
    // tanh(y) = 1 - 2/(exp(2y)+1); |err vs erf-gelu| ~1e-3 << 0.1 threshold
    float x2 = x * x;
    float y  = 0.7978845608f * x * fmaf(0.044715f, x2, 1.0f);
    float e  = __expf(2.0f * y);
    float t  = 1.0f - 2.0f * __builtin_amdgcn_rcpf(e + 1.0f);
    return 0.5f * x * (1.0f + t);
}

// Kernel 1: QKV projection. grid (BN, 3, 4), block 256.
__global__ __launch_bounds__(256)
void qkv_kernel(const float* __restrict__ padded, const float* __restrict__ tok,
                const float* __restrict__ Wq, const float* __restrict__ bq,
                const float* __restrict__ Wk, const float* __restrict__ bk,
                const float* __restrict__ Wv, const float* __restrict__ bv,
                float* __restrict__ Qo, float* __restrict__ KTo, float* __restrict__ Vo) {
    const int s = blockIdx.x;
    const int mat = blockIdx.y;
    const int chunk = blockIdx.z;
    const float* W = (mat == 0) ? Wq : (mat == 1) ? Wk : Wv;
    const float* bias = (mat == 0) ? bq : (mat == 1) ? bk : bv;

    __shared__ float x_tile[32][D];
    const int tid = threadIdx.x;
    for (int idx = tid; idx < 32 * D; idx += 256) {
        int r = idx >> 7, c = idx & 127;
        int i = chunk * 32 + r;
        x_tile[r][c] = (i == 0) ? tok[c] : padded[(size_t)s * TT * D + (size_t)(i - 1) * D + c];
    }
    __syncthreads();

    const int c = tid & 127;
    const int rg = tid >> 7;   // 0 or 1
    const int r0 = rg * 16;
    float acc[16];
    const float bc = bias[c];
#pragma unroll
    for (int r = 0; r < 16; ++r) acc[r] = bc;
    for (int d = 0; d < D; ++d) {
        float wv = W[d * D + c];
#pragma unroll
        for (int r = 0; r < 16; ++r) acc[r] = fmaf(x_tile[r0 + r][d], wv, acc[r]);
    }
    size_t base = (size_t)s * L * D;
    if (mat == 1) {
        for (int r = 0; r < 16; ++r)
            KTo[base + (size_t)c * L + (size_t)(chunk * 32 + r0 + r)] = acc[r];
    } else {
        float* outp = (mat == 0) ? Qo : Vo;
        for (int r = 0; r < 16; ++r)
            outp[base + (size_t)(chunk * 32 + r0 + r) * D + c] = acc[r];
    }
}

// Kernel 2: one block per (i, s); 128 threads.
// Pass 1: thread j = key index (features, bias MLP, logits, softmax).
// Pass 2: thread j = hidden channel c (recompute g[jj][c] on the fly, fused
//         with the V reduction) -> no g materialization, no bank conflicts.
__global__ __launch_bounds__(128, 4)
void attn_kernel(const float* __restrict__ padded, const int* __restrict__ masks,
                 const float* __restrict__ pos3d,
                 const float* __restrict__ gamma, const float* __restrict__ beta,
                 const float* __restrict__ tok,
                 const float* __restrict__ Wb1, const float* __restrict__ bb1,
                 const float* __restrict__ Wb2, const float* __restrict__ bb2,
                 const float* __restrict__ Wv1, const float* __restrict__ bv1,
                 const float* __restrict__ Wv2, const float* __restrict__ bv2,
                 const float* __restrict__ Q, const float* __restrict__ KT,
                 const float* __restrict__ V,
                 float* __restrict__ out) {
    const int i = blockIdx.x;
    const int s = blockIdx.y;
    const int j = threadIdx.x;
    const int wave = j >> 6;
    const int h = j >> 4;            // head owning output channel j

    __shared__ float wb1a[64][4];    // Wb1 rows 0..3 (dist folded into row3)
    __shared__ float wb1b[64][4];    // {Wb1 row5 (dist2), bb1, 0, 0}
    __shared__ float wb2s[64][8];
    __shared__ float q_lds[D];
    __shared__ float feat_lds[L][8]; // {dx,dy,dz,dist,dist2,-,-,-}
    __shared__ float w_lds[L][8];    // softmax weights, [j][h]
    __shared__ float gs_lds[NH][D + 1];
    __shared__ float redm[2][NH];
    __shared__ float reds[2][NH];
    __shared__ float red2[2][2];

    // per-thread register weights for the rel-val hidden channel j
    const float rv0 = Wv1[0 * 128 + j];
    const float rv1 = Wv1[1 * 128 + j];
    const float rv2 = Wv1[2 * 128 + j];
    const float rv3 = Wv1[3 * 128 + j] + Wv1[4 * 128 + j];
    const float rv4 = Wv1[5 * 128 + j];
    const float rbv = bv1[j];

    if (j < 64) {
        const int u = j;
        wb1a[u][0] = Wb1[0 * 64 + u];
        wb1a[u][1] = Wb1[1 * 64 + u];
        wb1a[u][2] = Wb1[2 * 64 + u];
        wb1a[u][3] = Wb1[3 * 64 + u] + Wb1[4 * 64 + u];
        wb1b[u][0] = Wb1[5 * 64 + u];
        wb1b[u][1] = bb1[u];
        wb1b[u][2] = 0.f;
        wb1b[u][3] = 0.f;
    }
    for (int idx = j; idx < 64 * 8; idx += 128) ((float*)wb2s)[idx] = Wb2[idx];
    q_lds[j] = Q[((size_t)s * L + (size_t)i) * D + j];

    // ---- relative features for pair (i, j) ----
    float pix = 0.f, piy = 0.f, piz = 0.f;
    if (i > 0) { const float* p = pos3d + ((size_t)s * TT + (i - 1)) * 3; pix = p[0]; piy = p[1]; piz = p[2]; }
    float pjx = 0.f, pjy = 0.f, pjz = 0.f;
    if (j > 0) { const float* p = pos3d + ((size_t)s * TT + (j - 1)) * 3; pjx = p[0]; pjy = p[1]; pjz = p[2]; }
    const float dx = pix - pjx, dy = piy - pjy, dz = piz - pjz;
    const float dist2 = dx * dx + dy * dy + dz * dz;
    const float dist = sqrtf(dist2);
    *(float4*)&feat_lds[j][0] = make_float4(dx, dy, dz, dist);
    feat_lds[j][4] = dist2;

    __syncthreads();

    // ---- rel bias MLP (only when i>0 && j>0) ----
    float bias[NH];
#pragma unroll
    for (int hh = 0; hh < NH; ++hh) bias[hh] = 0.f;
    if (i > 0 && j > 0) {
#pragma unroll 4
        for (int u = 0; u < 64; ++u) {
            float4 wa = *(const float4*)&wb1a[u][0];
            float4 wb = *(const float4*)&wb1b[u][0];
            float hv = wb.y;
            hv = fmaf(dx, wa.x, hv);
            hv = fmaf(dy, wa.y, hv);
            hv = fmaf(dz, wa.z, hv);
            hv = fmaf(dist, wa.w, hv);
            hv = fmaf(dist2, wb.x, hv);
            hv = fast_gelu(hv);
            float4 w2a = *(const float4*)&wb2s[u][0];
            float4 w2b = *(const float4*)&wb2s[u][4];
            bias[0] = fmaf(hv, w2a.x, bias[0]);
            bias[1] = fmaf(hv, w2a.y, bias[1]);
            bias[2] = fmaf(hv, w2a.z, bias[2]);
            bias[3] = fmaf(hv, w2a.w, bias[3]);
            bias[4] = fmaf(hv, w2b.x, bias[4]);
            bias[5] = fmaf(hv, w2b.y, bias[5]);
            bias[6] = fmaf(hv, w2b.z, bias[6]);
            bias[7] = fmaf(hv, w2b.w, bias[7]);
        }
#pragma unroll
        for (int hh = 0; hh < NH; ++hh) bias[hh] += bb2[hh];
    }

    // ---- logits: q . k per head via K^T (coalesced in j) ----
    const float* KTs = KT + (size_t)s * L * D;
    float l[NH];
#pragma unroll
    for (int hh = 0; hh < NH; ++hh) {
        float acc = 0.f;
#pragma unroll
        for (int dq = 0; dq < 4; ++dq) {
            float4 qv = *(const float4*)&q_lds[hh * 16 + dq * 4];
            const float* kp = KTs + (size_t)(hh * 16 + dq * 4) * L + j;
            acc = fmaf(qv.x, kp[0 * L], acc);
            acc = fmaf(qv.y, kp[1 * L], acc);
            acc = fmaf(qv.z, kp[2 * L], acc);
            acc = fmaf(qv.w, kp[3 * L], acc);
        }
        l[hh] = acc;
    }
    const int keep = (j == 0) ? 1 : masks[(size_t)s * TT + (j - 1)];
#pragma unroll
    for (int hh = 0; hh < NH; ++hh) {
        l[hh] = fmaf(l[hh], 0.25f, bias[hh]);
        if (!keep) l[hh] = -3.0e38f;
    }

    // ---- softmax across the 128 threads (2 waves) ----
    float m[NH];
#pragma unroll
    for (int hh = 0; hh < NH; ++hh) {
        float v = l[hh];
        for (int off = 32; off >= 1; off >>= 1) v = fmaxf(v, __shfl_xor(v, off, 64));
        m[hh] = v;
    }
    if ((j & 63) == 0) {
#pragma unroll
        for (int hh = 0; hh < NH; ++hh) redm[wave][hh] = m[hh];
    }
    __syncthreads();
#pragma unroll
    for (int hh = 0; hh < NH; ++hh) m[hh] = fmaxf(redm[0][hh], redm[1][hh]);

    float p[NH];
#pragma unroll
    for (int hh = 0; hh < NH; ++hh) {
        p[hh] = __expf(l[hh] - m[hh]);
        float v = p[hh];
        for (int off = 32; off >= 1; off >>= 1) v += __shfl_xor(v, off, 64);
        if ((j & 63) == 0) reds[wave][hh] = v;
    }
    __syncthreads();
    {
        float inv[NH];
#pragma unroll
        for (int hh = 0; hh < NH; ++hh) inv[hh] = __builtin_amdgcn_rcpf(reds[0][hh] + reds[1][hh]);
        float4 wlo = make_float4(p[0] * inv[0], p[1] * inv[1], p[2] * inv[2], p[3] * inv[3]);
        float4 whi = make_float4(p[4] * inv[4], p[5] * inv[5], p[6] * inv[6], p[7] * inv[7]);
        *(float4*)&w_lds[j][0] = wlo;
        *(float4*)&w_lds[j][4] = whi;
    }
    __syncthreads();   // w_lds + feat_lds ready

    // ---- pass 2: thread j = output/hidden channel; fused V + g reduction ----
    const float* Vs = V + (size_t)s * L * D;
    float a1 = w_lds[0][h] * Vs[j];     // jj = 0 term (g excluded at j==0)
    float a2 = 0.f;
    if (i > 0) {
        float gs[8];
#pragma unroll
        for (int x = 0; x < 8; ++x) gs[x] = 0.f;
#pragma unroll 2
        for (int jj = 1; jj < L; ++jj) {
            float4 fa = *(const float4*)&feat_lds[jj][0];   // broadcast
            float f5 = feat_lds[jj][4];
            float wown = w_lds[jj][h];
            float vv = Vs[(size_t)jj * D + j];
            a1 = fmaf(wown, vv, a1);
            float hv = rbv;
            hv = fmaf(fa.x, rv0, hv);
            hv = fmaf(fa.y, rv1, hv);
            hv = fmaf(fa.z, rv2, hv);
            hv = fmaf(fa.w, rv3, hv);
            hv = fmaf(f5, rv4, hv);
            float g = fast_gelu(hv);
            float4 wa = *(const float4*)&w_lds[jj][0];      // broadcast
            float4 wb = *(const float4*)&w_lds[jj][4];
            gs[0] = fmaf(wa.x, g, gs[0]);
            gs[1] = fmaf(wa.y, g, gs[1]);
            gs[2] = fmaf(wa.z, g, gs[2]);
            gs[3] = fmaf(wa.w, g, gs[3]);
            gs[4] = fmaf(wb.x, g, gs[4]);
            gs[5] = fmaf(wb.y, g, gs[5]);
            gs[6] = fmaf(wb.z, g, gs[6]);
            gs[7] = fmaf(wb.w, g, gs[7]);
        }
#pragma unroll
        for (int x = 0; x < 8; ++x) gs_lds[x][j] = gs[x];
    } else {
        for (int jj = 1; jj < L; ++jj)
            a1 = fmaf(w_lds[jj][h], Vs[(size_t)jj * D + j], a1);
    }
    __syncthreads();

    if (i > 0) {
        const float S1 = 1.0f - w_lds[0][h];
        float acc = 0.f;
#pragma unroll 4
        for (int cc = 0; cc < D; ++cc)
            acc = fmaf(gs_lds[h][cc], Wv2[(size_t)cc * D + j], acc);
        a2 = fmaf(S1, bv2[j], acc);
    }
    const float attn = a1 + a2;

    // ---- outputs ----
    if (i == 0) {
        float st = attn + tok[j];
        float sum = st, sum2 = st * st;
        for (int off = 32; off >= 1; off >>= 1) {
            sum += __shfl_xor(sum, off, 64);
            sum2 += __shfl_xor(sum2, off, 64);
        }
        if ((j & 63) == 0) { red2[wave][0] = sum; red2[wave][1] = sum2; }
        __syncthreads();
        sum = red2[0][0] + red2[1][0];
        sum2 = red2[0][1] + red2[1][1];
        const float mu = sum * (1.0f / 128.0f);
        const float var = sum2 * (1.0f / 128.0f) - mu * mu;
        const float y = (st - mu) * rsqrtf(var + 1e-5f) * gamma[j] + beta[j];
        out[(size_t)BN * TT * D + (size_t)s * D + j] = y;
    } else {
        const size_t o = (size_t)s * TT * D + (size_t)(i - 1) * D + j;
        out[o] = attn + padded[o];
    }
}

extern "C" void kernel_launch(void* const* d_in, const int* in_sizes, int n_in,
                              void* d_out, int out_size, void* d_ws, size_t ws_size,
                              hipStream_t stream) {
    const float* padded = (const float*)d_in[0];
    const int*   masks  = (const int*)d_in[1];
    const float* pos3d  = (const float*)d_in[2];
    const float* Wq = (const float*)d_in[3];
    const float* bq = (const float*)d_in[4];
    const float* Wk = (const float*)d_in[5];
    const float* bk = (const float*)d_in[6];
    const float* Wv = (const float*)d_in[7];
    const float* bv = (const float*)d_in[8];
    const float* gamma = (const float*)d_in[9];
    const float* beta  = (const float*)d_in[10];
    const float* tok   = (const float*)d_in[11];
    const float* Wb1 = (const float*)d_in[12];
    const float* bb1 = (const float*)d_in[13];
    const float* Wb2 = (const float*)d_in[14];
    const float* bb2 = (const float*)d_in[15];
    const float* Wv1 = (const float*)d_in[16];
    const float* bv1 = (const float*)d_in[17];
    const float* Wv2 = (const float*)d_in[18];
    const float* bv2 = (const float*)d_in[19];
    float* out = (float*)d_out;

    float* Q  = (float*)d_ws;
    float* KT = Q + (size_t)BN * L * D;
    float* Vw = KT + (size_t)BN * L * D;

    qkv_kernel<<<dim3(BN, 3, 4), 256, 0, stream>>>(padded, tok, Wq, bq, Wk, bk, Wv, bv, Q, KT, Vw);
    attn_kernel<<<dim3(L, BN), 128, 0, stream>>>(padded, masks, pos3d, gamma, beta, tok,
                                                 Wb1, bb1, Wb2, bb2, Wv1, bv1, Wv2, bv2,
                                                 Q, KT, Vw, out);
}

// Round 3
// 268.231 us; speedup vs baseline: 1.5844x; 1.5844x over previous
//
#include <hip/hip_runtime.h>
#include <hip/hip_bf16.h>
#include <math.h>

#define BN 32
#define L 128
#define D 128
#define TT 127
#define NH 8

__device__ __forceinline__ float fast_gelu(float x) {
    // tanh-form gelu; |err vs erf-gelu| ~1e-3 << 0.1 threshold
    float x2 = x * x;
    float y  = 0.7978845608f * x * fmaf(0.044715f, x2, 1.0f);
    float e  = __expf(2.0f * y);
    float t  = 1.0f - 2.0f * __builtin_amdgcn_rcpf(e + 1.0f);
    return 0.5f * x * (1.0f + t);
}

// Kernel 1: QKV projection. grid (BN, 3, 4), block 256.
__global__ __launch_bounds__(256)
void qkv_kernel(const float* __restrict__ padded, const float* __restrict__ tok,
                const float* __restrict__ Wq, const float* __restrict__ bq,
                const float* __restrict__ Wk, const float* __restrict__ bk,
                const float* __restrict__ Wv, const float* __restrict__ bv,
                float* __restrict__ Qo, float* __restrict__ KTo, float* __restrict__ Vo) {
    const int s = blockIdx.x;
    const int mat = blockIdx.y;
    const int chunk = blockIdx.z;
    const float* W = (mat == 0) ? Wq : (mat == 1) ? Wk : Wv;
    const float* bias = (mat == 0) ? bq : (mat == 1) ? bk : bv;

    __shared__ float x_tile[32][D];
    const int tid = threadIdx.x;
    for (int idx = tid; idx < 32 * D; idx += 256) {
        int r = idx >> 7, c = idx & 127;
        int i = chunk * 32 + r;
        x_tile[r][c] = (i == 0) ? tok[c] : padded[(size_t)s * TT * D + (size_t)(i - 1) * D + c];
    }
    __syncthreads();

    const int c = tid & 127;
    const int rg = tid >> 7;   // 0 or 1
    const int r0 = rg * 16;
    float acc[16];
    const float bc = bias[c];
#pragma unroll
    for (int r = 0; r < 16; ++r) acc[r] = bc;
    for (int d = 0; d < D; ++d) {
        float wv = W[d * D + c];
#pragma unroll
        for (int r = 0; r < 16; ++r) acc[r] = fmaf(x_tile[r0 + r][d], wv, acc[r]);
    }
    size_t base = (size_t)s * L * D;
    if (mat == 1) {
        for (int r = 0; r < 16; ++r)
            KTo[base + (size_t)c * L + (size_t)(chunk * 32 + r0 + r)] = acc[r];
    } else {
        float* outp = (mat == 0) ? Qo : Vo;
        for (int r = 0; r < 16; ++r)
            outp[base + (size_t)(chunk * 32 + r0 + r) * D + c] = acc[r];
    }
}

// Kernel 2: one block per (s, i); 128 threads; 1-D grid with XCD-aware
// swizzle so each XCD's L2 only sees 4 sequences (V/KT/Q panels hot in L2).
__global__ __launch_bounds__(128, 4)
void attn_kernel(const float* __restrict__ padded, const int* __restrict__ masks,
                 const float* __restrict__ pos3d,
                 const float* __restrict__ gamma, const float* __restrict__ beta,
                 const float* __restrict__ tok,
                 const float* __restrict__ Wb1, const float* __restrict__ bb1,
                 const float* __restrict__ Wb2, const float* __restrict__ bb2,
                 const float* __restrict__ Wv1, const float* __restrict__ bv1,
                 const float* __restrict__ Wv2, const float* __restrict__ bv2,
                 const float* __restrict__ Q, const float* __restrict__ KT,
                 const float* __restrict__ V,
                 float* __restrict__ out) {
    // ---- XCD-aware bijective swizzle: 4096 = 8 XCDs x (4 s x 128 i) ----
    const int bid = blockIdx.x;
    const int xcd = bid & 7;
    const int local = bid >> 3;          // 0..511 within this XCD
    const int s = xcd * 4 + (local >> 7);
    const int i = local & 127;

    const int j = threadIdx.x;
    const int wave = j >> 6;
    const int h = j >> 4;            // head owning output channel j

    __shared__ float wb1a[64][4];    // Wb1 rows 0..3 (dist folded into row3)
    __shared__ float wb1b[64][4];    // {Wb1 row5 (dist2), bb1, 0, 0}
    __shared__ float wb2s[64][8];
    __shared__ float q_lds[D];
    __shared__ float feat_lds[L][8]; // {dx,dy,dz,dist,dist2,-,-,-}
    __shared__ float w_lds[L][8];    // softmax weights, [j][h]
    __shared__ float gs_lds[NH][D + 1];
    __shared__ float redm[2][NH];
    __shared__ float reds[2][NH];
    __shared__ float red2[2][2];

    // per-thread register weights for the rel-val hidden channel j
    const float rv0 = Wv1[0 * 128 + j];
    const float rv1 = Wv1[1 * 128 + j];
    const float rv2 = Wv1[2 * 128 + j];
    const float rv3 = Wv1[3 * 128 + j] + Wv1[4 * 128 + j];
    const float rv4 = Wv1[5 * 128 + j];
    const float rbv = bv1[j];

    if (j < 64) {
        const int u = j;
        wb1a[u][0] = Wb1[0 * 64 + u];
        wb1a[u][1] = Wb1[1 * 64 + u];
        wb1a[u][2] = Wb1[2 * 64 + u];
        wb1a[u][3] = Wb1[3 * 64 + u] + Wb1[4 * 64 + u];
        wb1b[u][0] = Wb1[5 * 64 + u];
        wb1b[u][1] = bb1[u];
        wb1b[u][2] = 0.f;
        wb1b[u][3] = 0.f;
    }
    for (int idx = j; idx < 64 * 8; idx += 128) ((float*)wb2s)[idx] = Wb2[idx];
    q_lds[j] = Q[((size_t)s * L + (size_t)i) * D + j];

    // ---- relative features for pair (i, j) ----
    float pix = 0.f, piy = 0.f, piz = 0.f;
    if (i > 0) { const float* p = pos3d + ((size_t)s * TT + (i - 1)) * 3; pix = p[0]; piy = p[1]; piz = p[2]; }
    float pjx = 0.f, pjy = 0.f, pjz = 0.f;
    if (j > 0) { const float* p = pos3d + ((size_t)s * TT + (j - 1)) * 3; pjx = p[0]; pjy = p[1]; pjz = p[2]; }
    const float dx = pix - pjx, dy = piy - pjy, dz = piz - pjz;
    const float dist2 = dx * dx + dy * dy + dz * dz;
    const float dist = sqrtf(dist2);
    *(float4*)&feat_lds[j][0] = make_float4(dx, dy, dz, dist);
    feat_lds[j][4] = dist2;

    __syncthreads();

    // ---- rel bias MLP (only when i>0 && j>0) ----
    float bias[NH];
#pragma unroll
    for (int hh = 0; hh < NH; ++hh) bias[hh] = 0.f;
    if (i > 0 && j > 0) {
#pragma unroll 4
        for (int u = 0; u < 64; ++u) {
            float4 wa = *(const float4*)&wb1a[u][0];
            float4 wb = *(const float4*)&wb1b[u][0];
            float hv = wb.y;
            hv = fmaf(dx, wa.x, hv);
            hv = fmaf(dy, wa.y, hv);
            hv = fmaf(dz, wa.z, hv);
            hv = fmaf(dist, wa.w, hv);
            hv = fmaf(dist2, wb.x, hv);
            hv = fast_gelu(hv);
            float4 w2a = *(const float4*)&wb2s[u][0];
            float4 w2b = *(const float4*)&wb2s[u][4];
            bias[0] = fmaf(hv, w2a.x, bias[0]);
            bias[1] = fmaf(hv, w2a.y, bias[1]);
            bias[2] = fmaf(hv, w2a.z, bias[2]);
            bias[3] = fmaf(hv, w2a.w, bias[3]);
            bias[4] = fmaf(hv, w2b.x, bias[4]);
            bias[5] = fmaf(hv, w2b.y, bias[5]);
            bias[6] = fmaf(hv, w2b.z, bias[6]);
            bias[7] = fmaf(hv, w2b.w, bias[7]);
        }
#pragma unroll
        for (int hh = 0; hh < NH; ++hh) bias[hh] += bb2[hh];
    }

    // ---- logits: q . k per head via K^T (coalesced in j) ----
    const float* KTs = KT + (size_t)s * L * D;
    float l[NH];
#pragma unroll
    for (int hh = 0; hh < NH; ++hh) {
        float acc = 0.f;
#pragma unroll
        for (int dq = 0; dq < 4; ++dq) {
            float4 qv = *(const float4*)&q_lds[hh * 16 + dq * 4];
            const float* kp = KTs + (size_t)(hh * 16 + dq * 4) * L + j;
            acc = fmaf(qv.x, kp[0 * L], acc);
            acc = fmaf(qv.y, kp[1 * L], acc);
            acc = fmaf(qv.z, kp[2 * L], acc);
            acc = fmaf(qv.w, kp[3 * L], acc);
        }
        l[hh] = acc;
    }
    const int keep = (j == 0) ? 1 : masks[(size_t)s * TT + (j - 1)];
#pragma unroll
    for (int hh = 0; hh < NH; ++hh) {
        l[hh] = fmaf(l[hh], 0.25f, bias[hh]);
        if (!keep) l[hh] = -3.0e38f;
    }

    // ---- softmax across the 128 threads (2 waves) ----
    float m[NH];
#pragma unroll
    for (int hh = 0; hh < NH; ++hh) {
        float v = l[hh];
        for (int off = 32; off >= 1; off >>= 1) v = fmaxf(v, __shfl_xor(v, off, 64));
        m[hh] = v;
    }
    if ((j & 63) == 0) {
#pragma unroll
        for (int hh = 0; hh < NH; ++hh) redm[wave][hh] = m[hh];
    }
    __syncthreads();
#pragma unroll
    for (int hh = 0; hh < NH; ++hh) m[hh] = fmaxf(redm[0][hh], redm[1][hh]);

    float p[NH];
#pragma unroll
    for (int hh = 0; hh < NH; ++hh) {
        p[hh] = __expf(l[hh] - m[hh]);
        float v = p[hh];
        for (int off = 32; off >= 1; off >>= 1) v += __shfl_xor(v, off, 64);
        if ((j & 63) == 0) reds[wave][hh] = v;
    }
    __syncthreads();
    {
        float inv[NH];
#pragma unroll
        for (int hh = 0; hh < NH; ++hh) inv[hh] = __builtin_amdgcn_rcpf(reds[0][hh] + reds[1][hh]);
        float4 wlo = make_float4(p[0] * inv[0], p[1] * inv[1], p[2] * inv[2], p[3] * inv[3]);
        float4 whi = make_float4(p[4] * inv[4], p[5] * inv[5], p[6] * inv[6], p[7] * inv[7]);
        *(float4*)&w_lds[j][0] = wlo;
        *(float4*)&w_lds[j][4] = whi;
    }
    __syncthreads();   // w_lds + feat_lds ready

    // ---- pass 2: thread j = output/hidden channel; fused V + g reduction ----
    const float* Vs = V + (size_t)s * L * D;
    float a1 = w_lds[0][h] * Vs[j];     // jj = 0 term (g excluded at j==0)
    float a2 = 0.f;
    if (i > 0) {
        float gs[8];
#pragma unroll
        for (int x = 0; x < 8; ++x) gs[x] = 0.f;
        int jj = 1;
        for (; jj + 3 < L; jj += 4) {
            // batch the 4 global V loads first: 4 loads in flight
            float vv0 = Vs[(size_t)(jj + 0) * D + j];
            float vv1 = Vs[(size_t)(jj + 1) * D + j];
            float vv2 = Vs[(size_t)(jj + 2) * D + j];
            float vv3 = Vs[(size_t)(jj + 3) * D + j];
#pragma unroll
            for (int t = 0; t < 4; ++t) {
                const int jt = jj + t;
                const float vv = (t == 0) ? vv0 : (t == 1) ? vv1 : (t == 2) ? vv2 : vv3;
                float4 fa = *(const float4*)&feat_lds[jt][0];   // broadcast
                float f5 = feat_lds[jt][4];
                a1 = fmaf(w_lds[jt][h], vv, a1);
                float hv = rbv;
                hv = fmaf(fa.x, rv0, hv);
                hv = fmaf(fa.y, rv1, hv);
                hv = fmaf(fa.z, rv2, hv);
                hv = fmaf(fa.w, rv3, hv);
                hv = fmaf(f5, rv4, hv);
                float g = fast_gelu(hv);
                float4 wa = *(const float4*)&w_lds[jt][0];      // broadcast
                float4 wb = *(const float4*)&w_lds[jt][4];
                gs[0] = fmaf(wa.x, g, gs[0]);
                gs[1] = fmaf(wa.y, g, gs[1]);
                gs[2] = fmaf(wa.z, g, gs[2]);
                gs[3] = fmaf(wa.w, g, gs[3]);
                gs[4] = fmaf(wb.x, g, gs[4]);
                gs[5] = fmaf(wb.y, g, gs[5]);
                gs[6] = fmaf(wb.z, g, gs[6]);
                gs[7] = fmaf(wb.w, g, gs[7]);
            }
        }
        for (; jj < L; ++jj) {
            float vv = Vs[(size_t)jj * D + j];
            float4 fa = *(const float4*)&feat_lds[jj][0];
            float f5 = feat_lds[jj][4];
            a1 = fmaf(w_lds[jj][h], vv, a1);
            float hv = rbv;
            hv = fmaf(fa.x, rv0, hv);
            hv = fmaf(fa.y, rv1, hv);
            hv = fmaf(fa.z, rv2, hv);
            hv = fmaf(fa.w, rv3, hv);
            hv = fmaf(f5, rv4, hv);
            float g = fast_gelu(hv);
            float4 wa = *(const float4*)&w_lds[jj][0];
            float4 wb = *(const float4*)&w_lds[jj][4];
            gs[0] = fmaf(wa.x, g, gs[0]);
            gs[1] = fmaf(wa.y, g, gs[1]);
            gs[2] = fmaf(wa.z, g, gs[2]);
            gs[3] = fmaf(wa.w, g, gs[3]);
            gs[4] = fmaf(wb.x, g, gs[4]);
            gs[5] = fmaf(wb.y, g, gs[5]);
            gs[6] = fmaf(wb.z, g, gs[6]);
            gs[7] = fmaf(wb.w, g, gs[7]);
        }
#pragma unroll
        for (int x = 0; x < 8; ++x) gs_lds[x][j] = gs[x];
    } else {
#pragma unroll 4
        for (int jj = 1; jj < L; ++jj)
            a1 = fmaf(w_lds[jj][h], Vs[(size_t)jj * D + j], a1);
    }
    __syncthreads();

    if (i > 0) {
        const float S1 = 1.0f - w_lds[0][h];
        float acc0 = 0.f, acc1 = 0.f, acc2 = 0.f, acc3 = 0.f;
#pragma unroll 8
        for (int cc = 0; cc < D; cc += 4) {
            float w0 = Wv2[(size_t)(cc + 0) * D + j];
            float w1 = Wv2[(size_t)(cc + 1) * D + j];
            float w2 = Wv2[(size_t)(cc + 2) * D + j];
            float w3 = Wv2[(size_t)(cc + 3) * D + j];
            acc0 = fmaf(gs_lds[h][cc + 0], w0, acc0);
            acc1 = fmaf(gs_lds[h][cc + 1], w1, acc1);
            acc2 = fmaf(gs_lds[h][cc + 2], w2, acc2);
            acc3 = fmaf(gs_lds[h][cc + 3], w3, acc3);
        }
        a2 = fmaf(S1, bv2[j], (acc0 + acc1) + (acc2 + acc3));
    }
    const float attn = a1 + a2;

    // ---- outputs ----
    if (i == 0) {
        float st = attn + tok[j];
        float sum = st, sum2 = st * st;
        for (int off = 32; off >= 1; off >>= 1) {
            sum += __shfl_xor(sum, off, 64);
            sum2 += __shfl_xor(sum2, off, 64);
        }
        if ((j & 63) == 0) { red2[wave][0] = sum; red2[wave][1] = sum2; }
        __syncthreads();
        sum = red2[0][0] + red2[1][0];
        sum2 = red2[0][1] + red2[1][1];
        const float mu = sum * (1.0f / 128.0f);
        const float var = sum2 * (1.0f / 128.0f) - mu * mu;
        const float y = (st - mu) * rsqrtf(var + 1e-5f) * gamma[j] + beta[j];
        out[(size_t)BN * TT * D + (size_t)s * D + j] = y;
    } else {
        const size_t o = (size_t)s * TT * D + (size_t)(i - 1) * D + j;
        out[o] = attn + padded[o];
    }
}

extern "C" void kernel_launch(void* const* d_in, const int* in_sizes, int n_in,
                              void* d_out, int out_size, void* d_ws, size_t ws_size,
                              hipStream_t stream) {
    const float* padded = (const float*)d_in[0];
    const int*   masks  = (const int*)d_in[1];
    const float* pos3d  = (const float*)d_in[2];
    const float* Wq = (const float*)d_in[3];
    const float* bq = (const float*)d_in[4];
    const float* Wk = (const float*)d_in[5];
    const float* bk = (const float*)d_in[6];
    const float* Wv = (const float*)d_in[7];
    const float* bv = (const float*)d_in[8];
    const float* gamma = (const float*)d_in[9];
    const float* beta  = (const float*)d_in[10];
    const float* tok   = (const float*)d_in[11];
    const float* Wb1 = (const float*)d_in[12];
    const float* bb1 = (const float*)d_in[13];
    const float* Wb2 = (const float*)d_in[14];
    const float* bb2 = (const float*)d_in[15];
    const float* Wv1 = (const float*)d_in[16];
    const float* bv1 = (const float*)d_in[17];
    const float* Wv2 = (const float*)d_in[18];
    const float* bv2 = (const float*)d_in[19];
    float* out = (float*)d_out;

    float* Q  = (float*)d_ws;
    float* KT = Q + (size_t)BN * L * D;
    float* Vw = KT + (size_t)BN * L * D;

    qkv_kernel<<<dim3(BN, 3, 4), 256, 0, stream>>>(padded, tok, Wq, bq, Wk, bk, Wv, bv, Q, KT, Vw);
    attn_kernel<<<dim3(L * BN), 128, 0, stream>>>(padded, masks, pos3d, gamma, beta, tok,
                                                  Wb1, bb1, Wb2, bb2, Wv1, bv1, Wv2, bv2,
                                                  Q, KT, Vw, out);
}

// Round 4
// 120.774 us; speedup vs baseline: 3.5189x; 2.2209x over previous
//
#include <hip/hip_runtime.h>
#include <hip/hip_bf16.h>
#include <math.h>

#define BN 32
#define L 128
#define D 128
#define TT 127
#define NH 8

__device__ __forceinline__ float fast_gelu(float x) {
    float x2 = x * x;
    float y  = 0.7978845608f * x * fmaf(0.044715f, x2, 1.0f);
    float e  = __expf(2.0f * y);
    float t  = 1.0f - 2.0f * __builtin_amdgcn_rcpf(e + 1.0f);
    return 0.5f * x * (1.0f + t);
}

__device__ __forceinline__ float bfu_lo(unsigned u) { return __uint_as_float(u << 16); }
__device__ __forceinline__ float bfu_hi(unsigned u) { return __uint_as_float(u & 0xffff0000u); }

// ---------------- K1: QKV projection. grid (BN, 3, 4), block 256 ----------------
__global__ __launch_bounds__(256)
void qkv_kernel(const float* __restrict__ padded, const float* __restrict__ tok,
                const float* __restrict__ Wq, const float* __restrict__ bq,
                const float* __restrict__ Wk, const float* __restrict__ bk,
                const float* __restrict__ Wv, const float* __restrict__ bv,
                float* __restrict__ Qo, float* __restrict__ Ko, float* __restrict__ Vo) {
    const int s = blockIdx.x;
    const int mat = blockIdx.y;
    const int chunk = blockIdx.z;
    const float* W = (mat == 0) ? Wq : (mat == 1) ? Wk : Wv;
    const float* bias = (mat == 0) ? bq : (mat == 1) ? bk : bv;
    float* outp = (mat == 0) ? Qo : (mat == 1) ? Ko : Vo;

    __shared__ float x_tile[32][D];
    const int tid = threadIdx.x;
    for (int idx = tid; idx < 32 * D; idx += 256) {
        int r = idx >> 7, c = idx & 127;
        int i = chunk * 32 + r;
        x_tile[r][c] = (i == 0) ? tok[c] : padded[(size_t)s * TT * D + (size_t)(i - 1) * D + c];
    }
    __syncthreads();

    const int c = tid & 127;
    const int rg = tid >> 7;
    const int r0 = rg * 16;
    float acc[16];
    const float bc = bias[c];
#pragma unroll
    for (int r = 0; r < 16; ++r) acc[r] = bc;
    for (int d = 0; d < D; ++d) {
        float wv = W[d * D + c];
#pragma unroll
        for (int r = 0; r < 16; ++r) acc[r] = fmaf(x_tile[r0 + r][d], wv, acc[r]);
    }
    size_t base = (size_t)s * L * D;
    for (int r = 0; r < 16; ++r)
        outp[base + (size_t)(chunk * 32 + r0 + r) * D + c] = acc[r];
}

// ---------------- K2: logits GEMM per (s,h). grid (BN, NH), block 256 ----------------
// LW[s][h][i][j] = 0.25 * q_i . k_j   (bf16)
__global__ __launch_bounds__(256)
void logits_kernel(const float* __restrict__ Q, const float* __restrict__ K,
                   __hip_bfloat16* __restrict__ LW) {
    const int s = blockIdx.x;
    const int h = blockIdx.y;
    const int tid = threadIdx.x;

    __shared__ float Qs[128][16];
    __shared__ float Ks[128][16];
    for (int e = tid; e < 2048; e += 256) {
        int i = e >> 4, d = e & 15;
        Qs[i][d] = Q[((size_t)s * L + i) * D + h * 16 + d];
        Ks[i][d] = K[((size_t)s * L + i) * D + h * 16 + d];
    }
    __syncthreads();

    const int j = tid & 127;
    const int half = tid >> 7;
    float4 k0 = *(const float4*)&Ks[j][0];
    float4 k1 = *(const float4*)&Ks[j][4];
    float4 k2 = *(const float4*)&Ks[j][8];
    float4 k3 = *(const float4*)&Ks[j][12];

    __hip_bfloat16* lw = LW + ((size_t)(s * NH + h) * L) * L;
    for (int ii = 0; ii < 64; ++ii) {
        const int i = half * 64 + ii;
        float4 q0 = *(const float4*)&Qs[i][0];
        float4 q1 = *(const float4*)&Qs[i][4];
        float4 q2 = *(const float4*)&Qs[i][8];
        float4 q3 = *(const float4*)&Qs[i][12];
        float acc = q0.x * k0.x + q0.y * k0.y + q0.z * k0.z + q0.w * k0.w;
        acc = fmaf(q1.x, k1.x, acc); acc = fmaf(q1.y, k1.y, acc);
        acc = fmaf(q1.z, k1.z, acc); acc = fmaf(q1.w, k1.w, acc);
        acc = fmaf(q2.x, k2.x, acc); acc = fmaf(q2.y, k2.y, acc);
        acc = fmaf(q2.z, k2.z, acc); acc = fmaf(q2.w, k2.w, acc);
        acc = fmaf(q3.x, k3.x, acc); acc = fmaf(q3.y, k3.y, acc);
        acc = fmaf(q3.w, k3.w, acc); acc = fmaf(q3.z, k3.z, acc);
        lw[(size_t)i * L + j] = __float2bfloat16(acc * 0.25f);
    }
}

// ---------------- K3: core per (s,i). grid (L, BN), block 128 ----------------
__global__ __launch_bounds__(128, 4)
void attn_kernel(const float* __restrict__ padded, const int* __restrict__ masks,
                 const float* __restrict__ pos3d,
                 const float* __restrict__ gamma, const float* __restrict__ beta,
                 const float* __restrict__ tok,
                 const float* __restrict__ Wb1, const float* __restrict__ bb1,
                 const float* __restrict__ Wb2, const float* __restrict__ bb2,
                 const float* __restrict__ Wv1, const float* __restrict__ bv1,
                 const float* __restrict__ bv2,
                 const float* __restrict__ V, const __hip_bfloat16* __restrict__ LW,
                 __hip_bfloat16* __restrict__ GS,
                 float* __restrict__ out) {
    const int i = blockIdx.x;
    const int s = blockIdx.y;
    const int j = threadIdx.x;
    const int wave = j >> 6;
    const int h = j >> 4;

    __shared__ float wb1a[64][4];
    __shared__ float wb1b[64][4];
    __shared__ float wb2s[64][8];
    __shared__ float feat_lds[L][8];
    __shared__ float w_lds[L][8];
    __shared__ float redm[2][NH];
    __shared__ float reds[2][NH];
    __shared__ float red2[2][2];

    // ---- issue logit loads early ----
    __hip_bfloat16 lraw[NH];
#pragma unroll
    for (int hh = 0; hh < NH; ++hh)
        lraw[hh] = LW[((size_t)(s * NH + hh) * L + i) * L + j];

    // per-thread rel-val hidden-channel weights
    const float rv0 = Wv1[0 * 128 + j];
    const float rv1 = Wv1[1 * 128 + j];
    const float rv2 = Wv1[2 * 128 + j];
    const float rv3 = Wv1[3 * 128 + j] + Wv1[4 * 128 + j];
    const float rv4 = Wv1[5 * 128 + j];
    const float rbv = bv1[j];

    if (j < 64) {
        const int u = j;
        wb1a[u][0] = Wb1[0 * 64 + u];
        wb1a[u][1] = Wb1[1 * 64 + u];
        wb1a[u][2] = Wb1[2 * 64 + u];
        wb1a[u][3] = Wb1[3 * 64 + u] + Wb1[4 * 64 + u];
        wb1b[u][0] = Wb1[5 * 64 + u];
        wb1b[u][1] = bb1[u];
        wb1b[u][2] = 0.f;
        wb1b[u][3] = 0.f;
    }
    for (int idx = j; idx < 64 * 8; idx += 128) ((float*)wb2s)[idx] = Wb2[idx];

    // ---- relative features ----
    float pix = 0.f, piy = 0.f, piz = 0.f;
    if (i > 0) { const float* p = pos3d + ((size_t)s * TT + (i - 1)) * 3; pix = p[0]; piy = p[1]; piz = p[2]; }
    float pjx = 0.f, pjy = 0.f, pjz = 0.f;
    if (j > 0) { const float* p = pos3d + ((size_t)s * TT + (j - 1)) * 3; pjx = p[0]; pjy = p[1]; pjz = p[2]; }
    const float dx = pix - pjx, dy = piy - pjy, dz = piz - pjz;
    const float dist2 = dx * dx + dy * dy + dz * dz;
    const float dist = sqrtf(dist2);
    *(float4*)&feat_lds[j][0] = make_float4(dx, dy, dz, dist);
    feat_lds[j][4] = dist2;

    __syncthreads();

    const float* Vs = V + (size_t)s * L * D;
    float bufA[16], bufB[16];
    float bias[NH];
#pragma unroll
    for (int hh = 0; hh < NH; ++hh) bias[hh] = 0.f;

    if (i > 0) {
        // preload V chunk 0 -> in flight across the MLP + softmax
#pragma unroll
        for (int t = 0; t < 16; ++t) bufA[t] = Vs[(size_t)t * D + j];

        if (j > 0) {
#pragma unroll 4
            for (int u = 0; u < 64; ++u) {
                float4 wa = *(const float4*)&wb1a[u][0];
                float4 wb = *(const float4*)&wb1b[u][0];
                float hv = wb.y;
                hv = fmaf(dx, wa.x, hv);
                hv = fmaf(dy, wa.y, hv);
                hv = fmaf(dz, wa.z, hv);
                hv = fmaf(dist, wa.w, hv);
                hv = fmaf(dist2, wb.x, hv);
                hv = fast_gelu(hv);
                float4 w2a = *(const float4*)&wb2s[u][0];
                float4 w2b = *(const float4*)&wb2s[u][4];
                bias[0] = fmaf(hv, w2a.x, bias[0]);
                bias[1] = fmaf(hv, w2a.y, bias[1]);
                bias[2] = fmaf(hv, w2a.z, bias[2]);
                bias[3] = fmaf(hv, w2a.w, bias[3]);
                bias[4] = fmaf(hv, w2b.x, bias[4]);
                bias[5] = fmaf(hv, w2b.y, bias[5]);
                bias[6] = fmaf(hv, w2b.z, bias[6]);
                bias[7] = fmaf(hv, w2b.w, bias[7]);
            }
#pragma unroll
            for (int hh = 0; hh < NH; ++hh) bias[hh] += bb2[hh];
        }
    }

    const int keep = (j == 0) ? 1 : masks[(size_t)s * TT + (j - 1)];
    float l[NH];
#pragma unroll
    for (int hh = 0; hh < NH; ++hh) {
        l[hh] = __bfloat162float(lraw[hh]) + bias[hh];
        if (!keep) l[hh] = -3.0e38f;
    }

    // ---- softmax across 128 threads ----
    float m[NH];
#pragma unroll
    for (int hh = 0; hh < NH; ++hh) {
        float v = l[hh];
        for (int off = 32; off >= 1; off >>= 1) v = fmaxf(v, __shfl_xor(v, off, 64));
        m[hh] = v;
    }
    if ((j & 63) == 0) {
#pragma unroll
        for (int hh = 0; hh < NH; ++hh) redm[wave][hh] = m[hh];
    }
    __syncthreads();
#pragma unroll
    for (int hh = 0; hh < NH; ++hh) m[hh] = fmaxf(redm[0][hh], redm[1][hh]);

    float p[NH];
#pragma unroll
    for (int hh = 0; hh < NH; ++hh) {
        p[hh] = __expf(l[hh] - m[hh]);
        float v = p[hh];
        for (int off = 32; off >= 1; off >>= 1) v += __shfl_xor(v, off, 64);
        if ((j & 63) == 0) reds[wave][hh] = v;
    }
    __syncthreads();
    {
        float inv[NH];
#pragma unroll
        for (int hh = 0; hh < NH; ++hh) inv[hh] = __builtin_amdgcn_rcpf(reds[0][hh] + reds[1][hh]);
        float4 wlo = make_float4(p[0] * inv[0], p[1] * inv[1], p[2] * inv[2], p[3] * inv[3]);
        float4 whi = make_float4(p[4] * inv[4], p[5] * inv[5], p[6] * inv[6], p[7] * inv[7]);
        *(float4*)&w_lds[j][0] = wlo;
        *(float4*)&w_lds[j][4] = whi;
    }
    __syncthreads();

    // ---- pass 2: thread j = channel; V-reduce + g-sum, 16-deep prefetch ----
    float a1 = 0.f;
    if (i > 0) {
        float gs[8];
#pragma unroll
        for (int x = 0; x < 8; ++x) gs[x] = 0.f;

#define CHUNK(BASE, BUFP, BUFL)                                                        \
    do {                                                                               \
        if ((BASE) + 16 < 128) {                                                       \
            _Pragma("unroll")                                                          \
            for (int t = 0; t < 16; ++t) BUFL[t] = Vs[(size_t)((BASE) + 16 + t) * D + j]; \
        }                                                                              \
        _Pragma("unroll")                                                              \
        for (int t = 0; t < 16; ++t) {                                                 \
            const int jt = (BASE) + t;                                                 \
            float4 fa = *(const float4*)&feat_lds[jt][0];                              \
            float f5 = feat_lds[jt][4];                                                \
            float wj = w_lds[jt][h];                                                   \
            a1 = fmaf(wj, BUFP[t], a1);                                                \
            float hv = rbv;                                                            \
            hv = fmaf(fa.x, rv0, hv);                                                  \
            hv = fmaf(fa.y, rv1, hv);                                                  \
            hv = fmaf(fa.z, rv2, hv);                                                  \
            hv = fmaf(fa.w, rv3, hv);                                                  \
            hv = fmaf(f5, rv4, hv);                                                    \
            float g = fast_gelu(hv);                                                   \
            if (jt > 0) {                                                              \
                float4 wa = *(const float4*)&w_lds[jt][0];                             \
                float4 wb = *(const float4*)&w_lds[jt][4];                             \
                gs[0] = fmaf(wa.x, g, gs[0]);                                          \
                gs[1] = fmaf(wa.y, g, gs[1]);                                          \
                gs[2] = fmaf(wa.z, g, gs[2]);                                          \
                gs[3] = fmaf(wa.w, g, gs[3]);                                          \
                gs[4] = fmaf(wb.x, g, gs[4]);                                          \
                gs[5] = fmaf(wb.y, g, gs[5]);                                          \
                gs[6] = fmaf(wb.z, g, gs[6]);                                          \
                gs[7] = fmaf(wb.w, g, gs[7]);                                          \
            }                                                                          \
        }                                                                              \
    } while (0)

        CHUNK(0,   bufA, bufB);
        CHUNK(16,  bufB, bufA);
        CHUNK(32,  bufA, bufB);
        CHUNK(48,  bufB, bufA);
        CHUNK(64,  bufA, bufB);
        CHUNK(80,  bufB, bufA);
        CHUNK(96,  bufA, bufB);
        CHUNK(112, bufB, bufA);
#undef CHUNK

        // write per-head g-sums (bf16)
#pragma unroll
        for (int x = 0; x < 8; ++x)
            GS[((size_t)(s * L + i) * NH + x) * D + j] = __float2bfloat16(gs[x]);

        const float S1 = 1.0f - w_lds[0][h];
        const size_t o = (size_t)s * TT * D + (size_t)(i - 1) * D + j;
        out[o] = a1 + S1 * bv2[j] + padded[o];
    } else {
        // cls row: a2 == 0 (rel_val row 0 zeroed) -> finish fully here with LN
#pragma unroll 4
        for (int jj = 0; jj < L; ++jj)
            a1 = fmaf(w_lds[jj][h], Vs[(size_t)jj * D + j], a1);
        float st = a1 + tok[j];
        float sum = st, sum2 = st * st;
        for (int off = 32; off >= 1; off >>= 1) {
            sum += __shfl_xor(sum, off, 64);
            sum2 += __shfl_xor(sum2, off, 64);
        }
        if ((j & 63) == 0) { red2[wave][0] = sum; red2[wave][1] = sum2; }
        __syncthreads();
        sum = red2[0][0] + red2[1][0];
        sum2 = red2[0][1] + red2[1][1];
        const float mu = sum * (1.0f / 128.0f);
        const float var = sum2 * (1.0f / 128.0f) - mu * mu;
        const float y = (st - mu) * rsqrtf(var + 1e-5f) * gamma[j] + beta[j];
        out[(size_t)BN * TT * D + (size_t)s * D + j] = y;
    }
}

// ---------------- K4: a2 = gs @ Wv2, added into out. grid (BN, NH), block 256 ----------------
__global__ __launch_bounds__(256)
void a2_kernel(const __hip_bfloat16* __restrict__ GS, const float* __restrict__ Wv2,
               float* __restrict__ out) {
    const int s = blockIdx.x;
    const int h = blockIdx.y;
    const int tid = threadIdx.x;

    __shared__ unsigned short gss[128][136];   // bf16 raw, padded rows (272B)
    __shared__ float wv2s[128][17];

    // stage gs rows (i=0 zeroed; never written by K3)
    for (int e = tid; e < 4096; e += 256) {
        int i = e >> 5, c4 = (e & 31) * 4;
        uint2 raw = make_uint2(0u, 0u);
        if (i > 0) raw = *(const uint2*)&GS[((size_t)(s * L + i) * NH + h) * D + c4];
        *(uint2*)&gss[i][c4] = raw;
    }
    for (int e = tid; e < 2048; e += 256) {
        int c = e >> 4, w = e & 15;
        wv2s[c][w] = Wv2[(size_t)c * D + h * 16 + w];
    }
    __syncthreads();

    const int cc = tid & 15;
    const int ig = tid >> 4;
    float acc[8];
#pragma unroll
    for (int r = 0; r < 8; ++r) acc[r] = 0.f;

    for (int c = 0; c < 128; c += 8) {
        float wv[8];
#pragma unroll
        for (int k = 0; k < 8; ++k) wv[k] = wv2s[c + k][cc];
#pragma unroll
        for (int r = 0; r < 8; ++r) {
            const int i = ig + 16 * r;
            uint4 raw = *(const uint4*)&gss[i][c];
            acc[r] = fmaf(bfu_lo(raw.x), wv[0], acc[r]);
            acc[r] = fmaf(bfu_hi(raw.x), wv[1], acc[r]);
            acc[r] = fmaf(bfu_lo(raw.y), wv[2], acc[r]);
            acc[r] = fmaf(bfu_hi(raw.y), wv[3], acc[r]);
            acc[r] = fmaf(bfu_lo(raw.z), wv[4], acc[r]);
            acc[r] = fmaf(bfu_hi(raw.z), wv[5], acc[r]);
            acc[r] = fmaf(bfu_lo(raw.w), wv[6], acc[r]);
            acc[r] = fmaf(bfu_hi(raw.w), wv[7], acc[r]);
        }
    }

#pragma unroll
    for (int r = 0; r < 8; ++r) {
        const int i = ig + 16 * r;
        if (i > 0) {
            const size_t o = (size_t)s * TT * D + (size_t)(i - 1) * D + h * 16 + cc;
            out[o] += acc[r];
        }
    }
}

extern "C" void kernel_launch(void* const* d_in, const int* in_sizes, int n_in,
                              void* d_out, int out_size, void* d_ws, size_t ws_size,
                              hipStream_t stream) {
    const float* padded = (const float*)d_in[0];
    const int*   masks  = (const int*)d_in[1];
    const float* pos3d  = (const float*)d_in[2];
    const float* Wq = (const float*)d_in[3];
    const float* bq = (const float*)d_in[4];
    const float* Wk = (const float*)d_in[5];
    const float* bk = (const float*)d_in[6];
    const float* Wv = (const float*)d_in[7];
    const float* bv = (const float*)d_in[8];
    const float* gamma = (const float*)d_in[9];
    const float* beta  = (const float*)d_in[10];
    const float* tok   = (const float*)d_in[11];
    const float* Wb1 = (const float*)d_in[12];
    const float* bb1 = (const float*)d_in[13];
    const float* Wb2 = (const float*)d_in[14];
    const float* bb2 = (const float*)d_in[15];
    const float* Wv1 = (const float*)d_in[16];
    const float* bv1 = (const float*)d_in[17];
    const float* Wv2 = (const float*)d_in[18];
    const float* bv2 = (const float*)d_in[19];
    float* out = (float*)d_out;

    float* Q  = (float*)d_ws;
    float* K  = Q + (size_t)BN * L * D;
    float* Vw = K + (size_t)BN * L * D;
    __hip_bfloat16* LW = (__hip_bfloat16*)(Vw + (size_t)BN * L * D);
    __hip_bfloat16* GS = LW + (size_t)BN * NH * L * L;

    qkv_kernel<<<dim3(BN, 3, 4), 256, 0, stream>>>(padded, tok, Wq, bq, Wk, bk, Wv, bv, Q, K, Vw);
    logits_kernel<<<dim3(BN, NH), 256, 0, stream>>>(Q, K, LW);
    attn_kernel<<<dim3(L, BN), 128, 0, stream>>>(padded, masks, pos3d, gamma, beta, tok,
                                                 Wb1, bb1, Wb2, bb2, Wv1, bv1, bv2,
                                                 Vw, LW, GS, out);
    a2_kernel<<<dim3(BN, NH), 256, 0, stream>>>(GS, Wv2, out);
}